// Round 1
// baseline (972.751 us; speedup 1.0000x reference)
//
#include <hip/hip_runtime.h>
#include <hip/hip_cooperative_groups.h>
#include <math.h>
#include <stdint.h>

#define D 128
#define EPS 1e-6f
typedef unsigned short u16;
namespace cg = cooperative_groups;

// ---------------------------------------------------------------------------
// state layout (floats), 16B-aligned base:
//   st[0..127]   : q
//   st[128..255] : q_plus
//   st[256..383] : hop accumulator (device atomicAdd targets)
//   st[384]      : ||q||   st[385] : ||q_plus||   st[386] : sum-of-exp
// Rules learned: no device fences after bulk writes (r6, ~100us); no global
// atomic scatters (r8, ~84ns/atomic); gather time ~= TCC bytes / 3.8 TB/s
// (r9); reducer grids <= 1024 blocks (r10); single-block serial gathers are
// ~60us latency traps — always preload ids + pair-encode (r11).
// r13 (this round): 15 serial graph nodes cost ~2x the actual work — the
// pipeline is dispatch-gap bound, so the whole thing becomes ONE cooperative
// kernel with grid.sync() phase boundaries; old kernels kept as fallback.
// ---------------------------------------------------------------------------

__device__ __forceinline__ float wave_sum(float v) {
#pragma unroll
    for (int off = 32; off > 0; off >>= 1) v += __shfl_xor(v, off, 64);
    return v;
}
__device__ __forceinline__ float halfwave_sum(float v) {
#pragma unroll
    for (int off = 16; off > 0; off >>= 1) v += __shfl_xor(v, off, 32);
    return v;
}
__device__ __forceinline__ float quarter_sum(float v) {
#pragma unroll
    for (int off = 8; off > 0; off >>= 1) v += __shfl_xor(v, off, 16);
    return v;
}

__device__ __forceinline__ float bf2f(u16 h) {
    union { unsigned u; float f; } x;
    x.u = ((unsigned)h) << 16;
    return x.f;
}
__device__ __forceinline__ float bflo(unsigned u) { return bf2f((u16)(u & 0xffff)); }
__device__ __forceinline__ float bfhi(unsigned u) { return bf2f((u16)(u >> 16)); }
__device__ __forceinline__ u16 f2bf(float f) {  // round-to-nearest-even
    union { float f; unsigned u; } x;
    x.f = f;
    unsigned u = x.u;
    return (u16)((u + 0x7fff + ((u >> 16) & 1)) >> 16);
}
__device__ __forceinline__ unsigned pack2(float a, float b) {
    return (unsigned)f2bf(a) | ((unsigned)f2bf(b) << 16);
}

// ===========================================================================
// ================= OLD MULTI-KERNEL PIPELINE (fallback) ====================
// ===========================================================================

__global__ void table_to_bf16_s(const float* __restrict__ src,
                                u16* __restrict__ dst, int V) {
    int i = blockIdx.x * blockDim.x + threadIdx.x;
    if (i < V * 64) {
        int v = i >> 6;
        int c2 = i & 63;
        float a = src[(long)v * D + 2 * c2];
        float b = src[(long)v * D + 2 * c2 + 1];
        int s = c2 >> 4;
        int p = c2 & 15;
        *(unsigned*)(dst + ((long)s * V + v) * 32 + 2 * p) = pack2(a, b);
    }
}

template <int L>
__global__ void kv_slice_pass(const u16* __restrict__ tslice,
                              const int* __restrict__ kids,
                              const int* __restrict__ vids, int N,
                              u16* __restrict__ vb_slice,
                              float* __restrict__ knp, int pass) {
    const int lane = threadIdx.x & 63;
    const int q = lane >> 4;
    const int ql = lane & 15;
    int gw = (int)((blockIdx.x * blockDim.x + threadIdx.x) >> 6);
    int nw = (int)((gridDim.x * blockDim.x) >> 6);
    const int ngroup = N >> 2;
    for (int g = gw; g < ngroup; g += nw) {
        const long ibase = (long)g * (4 * L);
        int kidA = kids[ibase + lane];
        int vidA = vids[ibase + lane];
        int kidB = (lane < 4 * L - 64) ? kids[ibase + 64 + lane] : 0;
        int vidB = (lane < 4 * L - 64) ? vids[ibase + 64 + lane] : 0;
        float k0 = 0.f, k1 = 0.f, v0 = 0.f, v1 = 0.f;
#pragma unroll
        for (int t = 0; t < L; ++t) {
            const int j = L * q + t;
            const int jb = j - 64;
            int kA = __shfl(kidA, j & 63, 64);
            int kB = __shfl(kidB, jb < 0 ? 0 : jb, 64);
            int vA = __shfl(vidA, j & 63, 64);
            int vB = __shfl(vidB, jb < 0 ? 0 : jb, 64);
            const int kj = (j < 64) ? kA : kB;
            const int vj = (j < 64) ? vA : vB;
            const unsigned ke = *(const unsigned*)(tslice + (long)kj * 32 + 2 * ql);
            const unsigned ve = *(const unsigned*)(tslice + (long)vj * 32 + 2 * ql);
            k0 += bflo(ke); k1 += bfhi(ke);
            v0 += bflo(ve); v1 += bfhi(ve);
        }
        const int row = 4 * g + q;
        *(unsigned*)(vb_slice + (long)row * 32 + 2 * ql) = pack2(v0, v1);
        float sq = quarter_sum(k0 * k0 + k1 * k1);
        if (ql == 0) {
            if (pass == 0) knp[row] = sq;
            else if (pass == 3) knp[row] = sqrtf(knp[row] + sq);
            else knp[row] += sq;
        }
    }
}

__global__ void a2_s(const u16* __restrict__ tbl_s, const float* __restrict__ st,
                     float* __restrict__ s, int V) {
    const int lane = threadIdx.x & 63;
    const int q = lane >> 4;
    const int ql = lane & 15;
    const float2 qp2 = *(const float2*)(st + 128 + 2 * lane);
    int gw = (int)((blockIdx.x * blockDim.x + threadIdx.x) >> 6);
    int nw = (int)((gridDim.x * blockDim.x) >> 6);
    for (int v = gw; v < V; v += nw) {
        const unsigned u = *(const unsigned*)(tbl_s + ((long)q * V + v) * 32 + 2 * ql);
        float d = bflo(u) * qp2.x + bfhi(u) * qp2.y;
        d = wave_sum(d);
        if (lane == 0) s[v] = d;
    }
}

__global__ void b2e(const float* __restrict__ s, const int* __restrict__ kids,
                    const float* __restrict__ knorms, const float* __restrict__ st,
                    float* __restrict__ e, int N) {
    __shared__ float se[4];
    const int tid = threadIdx.x;
    const int row = blockIdx.x * blockDim.x + tid;
    const float qpn = st[385];
    float ev = 0.f;
    if (row < N) {
        const int4* kp = (const int4*)(kids + (long)row * 20);
        int4 k0 = kp[0], k1 = kp[1], k2 = kp[2], k3 = kp[3], k4 = kp[4];
        float dot = s[k0.x] + s[k0.y] + s[k0.z] + s[k0.w] +
                    s[k1.x] + s[k1.y] + s[k1.z] + s[k1.w] +
                    s[k2.x] + s[k2.y] + s[k2.z] + s[k2.w] +
                    s[k3.x] + s[k3.y] + s[k3.z] + s[k3.w] +
                    s[k4.x] + s[k4.y] + s[k4.z] + s[k4.w];
        const float c = dot / fmaxf(knorms[row] * qpn, EPS);
        ev = __expf(c);
        e[row] = ev;
    }
    float et = wave_sum(ev);
    if ((tid & 63) == 0) se[tid >> 6] = et;
    __syncthreads();
    if (tid == 0) atomicAdd((float*)&st[386], se[0] + se[1] + se[2] + se[3]);
}

__global__ void cv_acc(const u16* __restrict__ vb, const float* __restrict__ e,
                       float* __restrict__ st, int N) {
    __shared__ float acc_s[128];
    const int tid = threadIdx.x;
    const int lane = tid & 63;
    const int half = lane >> 5;
    const int hl = lane & 31;
    const int s4 = hl >> 3;
    const int w8 = hl & 7;
    int gw = (int)((blockIdx.x * blockDim.x + tid) >> 6);
    int nw = (int)((gridDim.x * blockDim.x) >> 6);
    float4 acc = {0.f, 0.f, 0.f, 0.f};
    const int npair = N >> 1;
    for (int p = gw; p < npair; p += nw) {
        const int i = 2 * p + half;
        float ei = e[i];
        const ushort4 vh = *(const ushort4*)(vb + ((long)s4 * N + i) * 32 + 4 * w8);
        acc.x += ei * bf2f(vh.x);
        acc.y += ei * bf2f(vh.y);
        acc.z += ei * bf2f(vh.z);
        acc.w += ei * bf2f(vh.w);
    }
    acc.x += __shfl_xor(acc.x, 32, 64);
    acc.y += __shfl_xor(acc.y, 32, 64);
    acc.z += __shfl_xor(acc.z, 32, 64);
    acc.w += __shfl_xor(acc.w, 32, 64);
    if (tid < 128) acc_s[tid] = 0.f;
    __syncthreads();
    const int ch = 32 * s4 + 4 * w8;
    if (half == 0) {
        atomicAdd(&acc_s[ch + 0], acc.x);
        atomicAdd(&acc_s[ch + 1], acc.y);
        atomicAdd(&acc_s[ch + 2], acc.z);
        atomicAdd(&acc_s[ch + 3], acc.w);
    }
    __syncthreads();
    if (tid < 128) atomicAdd(&st[256 + tid], acc_s[tid]);
}

__global__ void encode_small_p(const float* __restrict__ emb,
                               const int* __restrict__ pers, int NP, int LP,
                               const int* __restrict__ xs, int LQ,
                               float* __restrict__ pers_rows,
                               float* __restrict__ pnorms,
                               float* __restrict__ st) {
    const int lane = threadIdx.x & 63;
    const int half = lane >> 5;
    const int hl = lane & 31;
    int gw = (int)((blockIdx.x * blockDim.x + threadIdx.x) >> 6);
    int nw = (int)((gridDim.x * blockDim.x) >> 6);
    const int npr = NP + 1;
    const int npairs = (npr + 1) >> 1;
    for (int p = gw; p < npairs; p += nw) {
        const int row = 2 * p + half;
        const bool valid = row < npr;
        const int rowc = valid ? row : NP;
        const bool isq = (rowc == NP);
        const int* ids = isq ? xs : (pers + (long)rowc * LP);
        const int L = isq ? LQ : LP;
        int myid = 0;
        if (hl < L) myid = ids[hl];
        float4 acc = {0.f, 0.f, 0.f, 0.f};
        for (int t = 0; t < L; ++t) {
            const int idx = __shfl(myid, (half << 5) + t, 64);
            const float4 e = *(const float4*)(emb + (long)idx * D + 4 * hl);
            acc.x += e.x; acc.y += e.y; acc.z += e.z; acc.w += e.w;
        }
        if (valid) {
            float* outp = isq ? st : (pers_rows + (long)rowc * D);
            *(float4*)(outp + 4 * hl) = acc;
            float sq = acc.x * acc.x + acc.y * acc.y + acc.z * acc.z + acc.w * acc.w;
            sq = halfwave_sum(sq);
            if (hl == 0) {
                if (isq) st[384] = sqrtf(sq);
                else pnorms[rowc] = sqrtf(sq);
            }
        }
    }
}

__global__ void persona_hop(const float* __restrict__ pers_rows,
                            const float* __restrict__ pnorms,
                            const float* __restrict__ W,
                            float* __restrict__ st, int NP) {
    __shared__ float qsh[D];
    __shared__ float att[64];
    __shared__ float qh[D];
    __shared__ float red[2];
    int tid = threadIdx.x;
    qsh[tid] = st[tid];
    __syncthreads();
    if (tid < NP) {
        float dot = 0.f;
        for (int d2 = 0; d2 < D; ++d2) dot += pers_rows[tid * D + d2] * qsh[d2];
        att[tid] = dot / fmaxf(pnorms[tid] * st[384], EPS);
    }
    __syncthreads();
    if (tid == 0) {
        float m = -1e30f;
        for (int p = 0; p < NP; ++p) m = fmaxf(m, att[p]);
        float s = 0.f;
        for (int p = 0; p < NP; ++p) { att[p] = __expf(att[p] - m); s += att[p]; }
        float inv = 1.f / s;
        for (int p = 0; p < NP; ++p) att[p] *= inv;
    }
    __syncthreads();
    float h = 0.f;
    for (int p = 0; p < NP; ++p) h += att[p] * pers_rows[p * D + tid];
    qh[tid] = qsh[tid] + h;
    __syncthreads();
    float qp = 0.f;
    for (int d2 = 0; d2 < D; ++d2) qp += W[tid * D + d2] * qh[d2];
    st[128 + tid] = qp;
    float sq = wave_sum(qp * qp);
    if ((tid & 63) == 0) red[tid >> 6] = sq;
    __syncthreads();
    if (tid == 0) st[385] = sqrtf(red[0] + red[1]);
    st[256 + tid] = 0.f;
    if (tid == 0) st[386] = 0.f;
}

__global__ void mid_hop(const float* __restrict__ W1, const float* __restrict__ W2,
                        const float* __restrict__ pers_rows,
                        const float* __restrict__ pnorms,
                        float* __restrict__ st, int NP) {
    __shared__ float qh[D];
    __shared__ float qsh[D];
    __shared__ float att[64];
    __shared__ float red[2];
    int tid = threadIdx.x;
    float inv = 1.f / st[386];
    qh[tid] = st[128 + tid] + st[256 + tid] * inv;
    __syncthreads();
    float qn = 0.f;
    for (int d2 = 0; d2 < D; ++d2) qn += W1[tid * D + d2] * qh[d2];
    qsh[tid] = qn;
    st[tid] = qn;
    float sq = wave_sum(qn * qn);
    if ((tid & 63) == 0) red[tid >> 6] = sq;
    __syncthreads();
    float qnorm = sqrtf(red[0] + red[1]);
    if (tid == 0) st[384] = qnorm;
    if (tid < NP) {
        float dot = 0.f;
        for (int d2 = 0; d2 < D; ++d2) dot += pers_rows[tid * D + d2] * qsh[d2];
        att[tid] = dot / fmaxf(pnorms[tid] * qnorm, EPS);
    }
    __syncthreads();
    if (tid == 0) {
        float m = -1e30f;
        for (int p = 0; p < NP; ++p) m = fmaxf(m, att[p]);
        float s = 0.f;
        for (int p = 0; p < NP; ++p) { att[p] = __expf(att[p] - m); s += att[p]; }
        float is = 1.f / s;
        for (int p = 0; p < NP; ++p) att[p] *= is;
    }
    __syncthreads();
    float h = 0.f;
    for (int p = 0; p < NP; ++p) h += att[p] * pers_rows[p * D + tid];
    qh[tid] = qsh[tid] + h;
    __syncthreads();
    float qp = 0.f;
    for (int d2 = 0; d2 < D; ++d2) qp += W2[tid * D + d2] * qh[d2];
    st[128 + tid] = qp;
    float sq2 = wave_sum(qp * qp);
    if ((tid & 63) == 0) red[tid >> 6] = sq2;
    __syncthreads();
    if (tid == 0) st[385] = sqrtf(red[0] + red[1]);
    st[256 + tid] = 0.f;
    if (tid == 0) st[386] = 0.f;
}

__global__ void finish_hop(const float* __restrict__ W, float* __restrict__ st) {
    __shared__ float qh[D];
    __shared__ float red[2];
    int tid = threadIdx.x;
    float inv = 1.f / st[386];
    qh[tid] = st[128 + tid] + st[256 + tid] * inv;
    __syncthreads();
    float qn = 0.f;
    for (int d2 = 0; d2 < D; ++d2) qn += W[tid * D + d2] * qh[d2];
    st[tid] = qn;
    float sq = wave_sum(qn * qn);
    if ((tid & 63) == 0) red[tid >> 6] = sq;
    __syncthreads();
    if (tid == 0) st[384] = sqrtf(red[0] + red[1]);
}

__global__ void k5_final(const float* __restrict__ cemb,
                         const int* __restrict__ cands, int NC,
                         const float* __restrict__ st, float* __restrict__ out) {
    const int lane = threadIdx.x & 63;
    const int half = lane >> 5;
    const int hl = lane & 31;
    const int gw = (int)((blockIdx.x * blockDim.x + threadIdx.x) >> 6);
    const int nw = (int)((gridDim.x * blockDim.x) >> 6);
    const float4 q4 = *(const float4*)(st + 4 * hl);
    const float qn = st[384];
    const int npair = (NC + 1) >> 1;
    for (int p = gw; p < npair; p += nw) {
        const int row = 2 * p + half;
        const bool valid = row < NC;
        const int rowc = valid ? row : (NC - 1);
        int myid = 0;
        if (hl < 20) myid = cands[(long)rowc * 20 + hl];
        float4 acc = {0.f, 0.f, 0.f, 0.f};
#pragma unroll
        for (int t = 0; t < 20; ++t) {
            const int idx = __shfl(myid, (half << 5) + t, 64);
            const float4 e = *(const float4*)(cemb + (long)idx * D + 4 * hl);
            acc.x += e.x; acc.y += e.y; acc.z += e.z; acc.w += e.w;
        }
        float dot = halfwave_sum(acc.x * q4.x + acc.y * q4.y +
                                 acc.z * q4.z + acc.w * q4.w);
        float nsq = halfwave_sum(acc.x * acc.x + acc.y * acc.y +
                                 acc.z * acc.z + acc.w * acc.w);
        if (valid && hl == 0) out[row] = dot / fmaxf(sqrtf(nsq) * qn, EPS);
    }
}

__global__ void big_att_rc(const float* __restrict__ emb,
                           const int* __restrict__ kids,
                           const int* __restrict__ vids,
                           float* __restrict__ st, int N) {
    __shared__ float s[129];
    const int tid = threadIdx.x;
    const int lane = tid & 63;
    const int half = lane >> 5;
    const int hl = lane & 31;
    const int gw = (int)((blockIdx.x * blockDim.x + tid) >> 6);
    const int nw = (int)((gridDim.x * blockDim.x) >> 6);
    const float4 qp = *(const float4*)(st + 128 + 4 * hl);
    const float qpn = st[385];
    float4 hacc = {0.f, 0.f, 0.f, 0.f};
    float esum = 0.f;
    const int npair = (N + 1) >> 1;
    for (int p = gw; p < npair; p += nw) {
        const int row = 2 * p + half;
        const bool valid = row < N;
        const int rowc = valid ? row : (N - 1);
        int kid = 0, vid = 0;
        if (hl < 20) {
            kid = kids[(long)rowc * 20 + hl];
            vid = vids[(long)rowc * 20 + hl];
        }
        float4 ka = {0.f, 0.f, 0.f, 0.f}, va = {0.f, 0.f, 0.f, 0.f};
#pragma unroll
        for (int t = 0; t < 20; ++t) {
            const int ki = __shfl(kid, (half << 5) + t, 64);
            const int vi = __shfl(vid, (half << 5) + t, 64);
            const float4 ke = *(const float4*)(emb + (long)ki * D + 4 * hl);
            const float4 ve = *(const float4*)(emb + (long)vi * D + 4 * hl);
            ka.x += ke.x; ka.y += ke.y; ka.z += ke.z; ka.w += ke.w;
            va.x += ve.x; va.y += ve.y; va.z += ve.z; va.w += ve.w;
        }
        float nsq = halfwave_sum(ka.x * ka.x + ka.y * ka.y + ka.z * ka.z + ka.w * ka.w);
        float dot = halfwave_sum(ka.x * qp.x + ka.y * qp.y + ka.z * qp.z + ka.w * qp.w);
        const float c = dot / fmaxf(sqrtf(nsq) * qpn, EPS);
        float e = __expf(c);
        if (!valid) e = 0.f;
        hacc.x += e * va.x; hacc.y += e * va.y;
        hacc.z += e * va.z; hacc.w += e * va.w;
        if (hl == 0) esum += e;
    }
    hacc.x += __shfl_xor(hacc.x, 32, 64);
    hacc.y += __shfl_xor(hacc.y, 32, 64);
    hacc.z += __shfl_xor(hacc.z, 32, 64);
    hacc.w += __shfl_xor(hacc.w, 32, 64);
    esum += __shfl_xor(esum, 32, 64);
    if (tid < 129) s[tid] = 0.f;
    __syncthreads();
    if (half == 0) {
        atomicAdd(&s[4 * hl + 0], hacc.x);
        atomicAdd(&s[4 * hl + 1], hacc.y);
        atomicAdd(&s[4 * hl + 2], hacc.z);
        atomicAdd(&s[4 * hl + 3], hacc.w);
        if (hl == 0) atomicAdd(&s[128], esum);
    }
    __syncthreads();
    if (tid < 128) atomicAdd(&st[256 + tid], s[tid]);
    if (tid == 128) atomicAdd(&st[386], s[128]);
}

// ===========================================================================
// ===================== COOPERATIVE MEGA-KERNEL (r13) =======================
// One dispatch; grid.sync() between phases. 256 thr/block; grid sized by the
// occupancy query (capped 1024, r10-compliant for the atomic reducer phase).
// Phase map:
//   S0 : K1 bf16 convert (blocks 0..nb-4)  ||  small encodes (last 3 blocks)
//   S1 : K2 slice0 (blocks 1..nb-1)        ||  persona_hop (block 0, hidden)
//   S2-S4 : K2 slices 1..3 (knp add / sqrt on pass 3)
//   S5 : a2 (s[v] = T16[v].q_plus)   S6 : fused b2e+cv (e never stored)
//   S7 : mid_hop (block 0)           S8-S10 : hop 2 (a2, attcv, finish)
//   S11: k5 candidate gather+cosine
// ===========================================================================

__device__ void persona_dev(const float* __restrict__ pers_rows,
                            const float* __restrict__ pnorms,
                            const float* __restrict__ W, float* __restrict__ st,
                            int NP, float* smem, int tid) {
    float* qsh = smem;          // 128
    float* qh = smem + 128;     // 128
    float* att = smem + 256;    // 64
    float* red = smem + 320;    // 2
    if (tid < D) qsh[tid] = st[tid];
    __syncthreads();
    if (tid < NP) {
        float dot = 0.f;
        const float* pr = pers_rows + (long)tid * D;
        for (int d2 = 0; d2 < D; ++d2) dot += pr[d2] * qsh[d2];
        att[tid] = dot / fmaxf(pnorms[tid] * st[384], EPS);
    }
    __syncthreads();
    if (tid == 0) {
        float m = -1e30f;
        for (int p = 0; p < NP; ++p) m = fmaxf(m, att[p]);
        float s = 0.f;
        for (int p = 0; p < NP; ++p) { att[p] = __expf(att[p] - m); s += att[p]; }
        float inv = 1.f / s;
        for (int p = 0; p < NP; ++p) att[p] *= inv;
    }
    __syncthreads();
    if (tid < D) {
        float h = 0.f;
        for (int p = 0; p < NP; ++p) h += att[p] * pers_rows[(long)p * D + tid];
        qh[tid] = qsh[tid] + h;
    }
    __syncthreads();
    float qp = 0.f;
    if (tid < D) {
        for (int d2 = 0; d2 < D; ++d2) qp += W[(long)tid * D + d2] * qh[d2];
        st[128 + tid] = qp;
    }
    float sq = wave_sum(qp * qp);
    if ((tid & 63) == 0 && tid < 128) red[tid >> 6] = sq;
    __syncthreads();
    if (tid == 0) st[385] = sqrtf(red[0] + red[1]);
    if (tid < D) st[256 + tid] = 0.f;
    if (tid == 0) st[386] = 0.f;
}

__device__ void mid_dev(const float* __restrict__ W1, const float* __restrict__ W2,
                        const float* __restrict__ pers_rows,
                        const float* __restrict__ pnorms,
                        float* __restrict__ st, int NP, float* smem, int tid) {
    float* qh = smem;
    float* qsh = smem + 128;
    float* att = smem + 256;
    float* red = smem + 320;
    const float inv = 1.f / st[386];
    if (tid < D) qh[tid] = st[128 + tid] + st[256 + tid] * inv;
    __syncthreads();
    float qn = 0.f;
    if (tid < D) {
        for (int d2 = 0; d2 < D; ++d2) qn += W1[(long)tid * D + d2] * qh[d2];
        qsh[tid] = qn;
        st[tid] = qn;
    }
    float sq = wave_sum(qn * qn);
    if ((tid & 63) == 0 && tid < 128) red[tid >> 6] = sq;
    __syncthreads();
    const float qnorm = sqrtf(red[0] + red[1]);
    if (tid == 0) st[384] = qnorm;
    if (tid < NP) {
        float dot = 0.f;
        for (int d2 = 0; d2 < D; ++d2) dot += pers_rows[(long)tid * D + d2] * qsh[d2];
        att[tid] = dot / fmaxf(pnorms[tid] * qnorm, EPS);
    }
    __syncthreads();
    if (tid == 0) {
        float m = -1e30f;
        for (int p = 0; p < NP; ++p) m = fmaxf(m, att[p]);
        float s = 0.f;
        for (int p = 0; p < NP; ++p) { att[p] = __expf(att[p] - m); s += att[p]; }
        float is = 1.f / s;
        for (int p = 0; p < NP; ++p) att[p] *= is;
    }
    __syncthreads();
    if (tid < D) {
        float h = 0.f;
        for (int p = 0; p < NP; ++p) h += att[p] * pers_rows[(long)p * D + tid];
        qh[tid] = qsh[tid] + h;
    }
    __syncthreads();
    float qp = 0.f;
    if (tid < D) {
        for (int d2 = 0; d2 < D; ++d2) qp += W2[(long)tid * D + d2] * qh[d2];
        st[128 + tid] = qp;
    }
    float sq2 = wave_sum(qp * qp);
    if ((tid & 63) == 0 && tid < 128) red[tid >> 6] = sq2;
    __syncthreads();
    if (tid == 0) st[385] = sqrtf(red[0] + red[1]);
    if (tid < D) st[256 + tid] = 0.f;
    if (tid == 0) st[386] = 0.f;
}

__device__ void finish_dev(const float* __restrict__ W, float* __restrict__ st,
                           float* smem, int tid) {
    float* qh = smem;
    float* red = smem + 320;
    const float inv = 1.f / st[386];
    if (tid < D) qh[tid] = st[128 + tid] + st[256 + tid] * inv;
    __syncthreads();
    float qn = 0.f;
    if (tid < D) {
        for (int d2 = 0; d2 < D; ++d2) qn += W[(long)tid * D + d2] * qh[d2];
        st[tid] = qn;
    }
    float sq = wave_sum(qn * qn);
    if ((tid & 63) == 0 && tid < 128) red[tid >> 6] = sq;
    __syncthreads();
    if (tid == 0) st[384] = sqrtf(red[0] + red[1]);
}

__device__ void kv_dev(const u16* __restrict__ tslice, const int* __restrict__ kids,
                       const int* __restrict__ vids, int N,
                       u16* __restrict__ vb_slice, float* __restrict__ knp,
                       int pass, int bb, int nbb, int tid) {
    const int lane = tid & 63;
    const int q = lane >> 4;
    const int ql = lane & 15;
    const int gw = (bb * 256 + tid) >> 6;
    const int nw = (nbb * 256) >> 6;
    const int ngroup = N >> 2;
    for (int g = gw; g < ngroup; g += nw) {
        const long ibase = (long)g * 80;
        int kidA = kids[ibase + lane];
        int vidA = vids[ibase + lane];
        int kidB = (lane < 16) ? kids[ibase + 64 + lane] : 0;
        int vidB = (lane < 16) ? vids[ibase + 64 + lane] : 0;
        float k0 = 0.f, k1 = 0.f, v0 = 0.f, v1 = 0.f;
#pragma unroll
        for (int t = 0; t < 20; ++t) {
            const int j = 20 * q + t;
            const int jb = j - 64;
            int kA = __shfl(kidA, j & 63, 64);
            int kB = __shfl(kidB, jb < 0 ? 0 : jb, 64);
            int vA = __shfl(vidA, j & 63, 64);
            int vB = __shfl(vidB, jb < 0 ? 0 : jb, 64);
            const int kj = (j < 64) ? kA : kB;
            const int vj = (j < 64) ? vA : vB;
            const unsigned ke = *(const unsigned*)(tslice + (long)kj * 32 + 2 * ql);
            const unsigned ve = *(const unsigned*)(tslice + (long)vj * 32 + 2 * ql);
            k0 += bflo(ke); k1 += bfhi(ke);
            v0 += bflo(ve); v1 += bfhi(ve);
        }
        const int row = 4 * g + q;
        *(unsigned*)(vb_slice + (long)row * 32 + 2 * ql) = pack2(v0, v1);
        float sq = quarter_sum(k0 * k0 + k1 * k1);
        if (ql == 0) {
            if (pass == 0) knp[row] = sq;
            else if (pass == 3) knp[row] = sqrtf(knp[row] + sq);
            else knp[row] += sq;
        }
    }
}

__device__ void a2_dev(const u16* __restrict__ tbl_s, const float* __restrict__ st,
                       float* __restrict__ s, int V, int bid, int nb, int tid) {
    const int lane = tid & 63;
    const int q = lane >> 4;
    const int ql = lane & 15;
    const float2 qp2 = *(const float2*)(st + 128 + 2 * lane);
    const int gw = (bid * 256 + tid) >> 6;
    const int nw = (nb * 256) >> 6;
    for (int v = gw; v < V; v += nw) {
        const unsigned u = *(const unsigned*)(tbl_s + ((long)q * V + v) * 32 + 2 * ql);
        float d = bflo(u) * qp2.x + bfhi(u) * qp2.y;
        d = wave_sum(d);
        if (lane == 0) s[v] = d;
    }
}

// fused b2e + cv: dot via s-gather (20 lanes), e in-register, accumulate e*v
__device__ void attcv_dev(const float* __restrict__ sv, const int* __restrict__ kids,
                          const float* __restrict__ knorms, const u16* __restrict__ vb,
                          float* __restrict__ st, int N, int bid, int nb, int tid,
                          float* smem) {
    const int lane = tid & 63;
    const int half = lane >> 5;
    const int hl = lane & 31;
    const int s4 = hl >> 3;
    const int w8 = hl & 7;
    const float qpn = st[385];
    const int gw = (bid * 256 + tid) >> 6;
    const int nw = (nb * 256) >> 6;
    float4 hacc = {0.f, 0.f, 0.f, 0.f};
    float esum = 0.f;
    const int npair = N >> 1;
    for (int p = gw; p < npair; p += nw) {
        const int i = 2 * p + half;
        float partial = 0.f;
        if (hl < 20) partial = sv[kids[(long)i * 20 + hl]];
        const float dot = halfwave_sum(partial);
        const float c = dot / fmaxf(knorms[i] * qpn, EPS);
        const float e = __expf(c);
        const ushort4 vh = *(const ushort4*)(vb + ((long)s4 * N + i) * 32 + 4 * w8);
        hacc.x += e * bf2f(vh.x);
        hacc.y += e * bf2f(vh.y);
        hacc.z += e * bf2f(vh.z);
        hacc.w += e * bf2f(vh.w);
        if (hl == 0) esum += e;
    }
    hacc.x += __shfl_xor(hacc.x, 32, 64);
    hacc.y += __shfl_xor(hacc.y, 32, 64);
    hacc.z += __shfl_xor(hacc.z, 32, 64);
    hacc.w += __shfl_xor(hacc.w, 32, 64);
    esum += __shfl_xor(esum, 32, 64);
    if (tid < 129) smem[tid] = 0.f;
    __syncthreads();
    if (half == 0) {
        const int ch = 32 * s4 + 4 * w8;
        atomicAdd(&smem[ch + 0], hacc.x);
        atomicAdd(&smem[ch + 1], hacc.y);
        atomicAdd(&smem[ch + 2], hacc.z);
        atomicAdd(&smem[ch + 3], hacc.w);
        if (hl == 0) atomicAdd(&smem[128], esum);
    }
    __syncthreads();
    if (tid < 128) atomicAdd(&st[256 + tid], smem[tid]);
    if (tid == 128) atomicAdd(&st[386], smem[128]);
    __syncthreads();
}

__device__ void k5_dev(const float* __restrict__ cemb, const int* __restrict__ cands,
                       int NC, const float* __restrict__ st, float* __restrict__ out,
                       int bid, int nb, int tid) {
    const int lane = tid & 63;
    const int half = lane >> 5;
    const int hl = lane & 31;
    const int gw = (bid * 256 + tid) >> 6;
    const int nw = (nb * 256) >> 6;
    const float4 q4 = *(const float4*)(st + 4 * hl);
    const float qn = st[384];
    const int npair = (NC + 1) >> 1;
    for (int p = gw; p < npair; p += nw) {
        const int row = 2 * p + half;
        const bool valid = row < NC;
        const int rowc = valid ? row : (NC - 1);
        int myid = 0;
        if (hl < 20) myid = cands[(long)rowc * 20 + hl];
        float4 acc = {0.f, 0.f, 0.f, 0.f};
#pragma unroll
        for (int t = 0; t < 20; ++t) {
            const int idx = __shfl(myid, (half << 5) + t, 64);
            const float4 e = *(const float4*)(cemb + (long)idx * D + 4 * hl);
            acc.x += e.x; acc.y += e.y; acc.z += e.z; acc.w += e.w;
        }
        float dot = halfwave_sum(acc.x * q4.x + acc.y * q4.y +
                                 acc.z * q4.z + acc.w * q4.w);
        float nsq = halfwave_sum(acc.x * acc.x + acc.y * acc.y +
                                 acc.z * acc.z + acc.w * acc.w);
        if (valid && hl == 0) out[row] = dot / fmaxf(sqrtf(nsq) * qn, EPS);
    }
}

__global__ void __launch_bounds__(256, 4) mega_kernel(
    const float* __restrict__ semb, const float* __restrict__ cemb,
    const int* __restrict__ xs, const int* __restrict__ cands,
    const int* __restrict__ pers, const int* __restrict__ keys,
    const int* __restrict__ values, const float* __restrict__ RW,
    const float* __restrict__ R2W, u16* __restrict__ tbl16s,
    u16* __restrict__ vb, float* __restrict__ knp, float* __restrict__ sv,
    float* __restrict__ enc_pers, float* __restrict__ pnorms,
    float* __restrict__ st, float* __restrict__ out,
    int V, int NMEM, int NCAND, int NPERS, int LQ) {
    cg::grid_group grid = cg::this_grid();
    __shared__ float smem[336];
    const int tid = threadIdx.x;
    const int bid = blockIdx.x;
    const int nb = gridDim.x;

    // ---- S0: K1 convert || small encodes (persona rows + q) on last 3 blocks
    if (bid < nb - 3) {
        const int stride = (nb - 3) * 256;
        const int n = V * 64;
        for (int i = bid * 256 + tid; i < n; i += stride) {
            const int v = i >> 6;
            const int c2 = i & 63;
            const float a = semb[(long)v * D + 2 * c2];
            const float b = semb[(long)v * D + 2 * c2 + 1];
            const int s = c2 >> 4;
            const int p = c2 & 15;
            *(unsigned*)(tbl16s + ((long)s * V + v) * 32 + 2 * p) = pack2(a, b);
        }
    } else {
        const int lane = tid & 63;
        const int half = lane >> 5;
        const int hl = lane & 31;
        const int w0 = (bid - (nb - 3)) * 4 + (tid >> 6);
        const int npr = NPERS + 1;
        const int npairs = (npr + 1) >> 1;
        for (int w = w0; w < npairs; w += 12) {
            const int row = 2 * w + half;
            const bool valid = row < npr;
            const int rowc = valid ? row : NPERS;
            const bool isq = (rowc == NPERS);
            const int* ids = isq ? xs : (pers + (long)rowc * 20);
            const int L = isq ? LQ : 20;
            int myid = 0;
            if (hl < L) myid = ids[hl];
            float4 acc = {0.f, 0.f, 0.f, 0.f};
            for (int t = 0; t < L; ++t) {
                const int idx = __shfl(myid, (half << 5) + t, 64);
                const float4 e = *(const float4*)(semb + (long)idx * D + 4 * hl);
                acc.x += e.x; acc.y += e.y; acc.z += e.z; acc.w += e.w;
            }
            if (valid) {
                float* outp = isq ? st : (enc_pers + (long)rowc * D);
                *(float4*)(outp + 4 * hl) = acc;
                float sq = acc.x * acc.x + acc.y * acc.y + acc.z * acc.z + acc.w * acc.w;
                sq = halfwave_sum(sq);
                if (hl == 0) {
                    if (isq) st[384] = sqrtf(sq);
                    else pnorms[rowc] = sqrtf(sq);
                }
            }
        }
    }
    grid.sync();

    // ---- S1..S4: K2 slice passes; persona_hop hidden under slice 0 on block 0
    for (int s = 0; s < 4; ++s) {
        if (s == 0 && bid == 0) {
            persona_dev(enc_pers, pnorms, RW, st, NPERS, smem, tid);
        } else {
            const int bb = (s == 0) ? bid - 1 : bid;
            const int nbb = (s == 0) ? nb - 1 : nb;
            kv_dev(tbl16s + (size_t)s * V * 32, keys, values, NMEM,
                   vb + (size_t)s * NMEM * 32, knp, s, bb, nbb, tid);
        }
        grid.sync();
    }

    // ---- hops 1 & 2
    for (int hop = 0; hop < 2; ++hop) {
        a2_dev(tbl16s, st, sv, V, bid, nb, tid);
        grid.sync();
        attcv_dev(sv, keys, knp, vb, st, NMEM, bid, nb, tid, smem);
        grid.sync();
        if (bid == 0) {
            if (hop == 0) mid_dev(RW, R2W, enc_pers, pnorms, st, NPERS, smem, tid);
            else finish_dev(R2W, st, smem, tid);
        }
        grid.sync();
    }

    // ---- S11: candidates
    k5_dev(cemb, cands, NCAND, st, out, bid, nb, tid);
}

static inline size_t align16(size_t b) { return (b + 15) & ~(size_t)15; }

extern "C" void kernel_launch(void* const* d_in, const int* in_sizes, int n_in,
                              void* d_out, int out_size, void* d_ws, size_t ws_size,
                              hipStream_t stream) {
    const int* xs = (const int*)d_in[0];
    const int* cands = (const int*)d_in[1];
    const int* pers = (const int*)d_in[2];
    const int* keys = (const int*)d_in[3];
    const int* values = (const int*)d_in[4];
    const float* semb = (const float*)d_in[6];
    const float* cemb = (const float*)d_in[7];
    const float* RW = (const float*)d_in[8];
    const float* R2W = (const float*)d_in[9];
    float* out = (float*)d_out;

    const int L = 20;
    const int LQ = in_sizes[0];
    const int VD = in_sizes[6];
    const int V = VD / D;
    const int NMEM = in_sizes[3] / L;
    const int NCAND = in_sizes[1] / L;
    const int NPERS = in_sizes[2] / L;

    size_t need = align16((size_t)VD * 2) + align16((size_t)NMEM * D * 2) +
                  align16((size_t)NMEM * 4) * 2 + align16((size_t)V * 4) +
                  align16((size_t)NPERS * D * 4) + align16((size_t)NPERS * 4) +
                  512 * 4;
    bool stored = (d_ws != nullptr) && (ws_size >= need) && (NMEM % 4 == 0) &&
                  ((VD & 3) == 0) && (LQ <= 32);

    const int THR = 256;
    char* base = (char*)d_ws;
    u16 *tbl16s = nullptr, *vb = nullptr;
    float *knp = nullptr, *sv = nullptr, *ev = nullptr;
    if (stored) {
        tbl16s = (u16*)base; base += align16((size_t)VD * 2);
        vb = (u16*)base;     base += align16((size_t)NMEM * D * 2);
        knp = (float*)base;  base += align16((size_t)NMEM * 4);
        ev = (float*)base;   base += align16((size_t)NMEM * 4);
        sv = (float*)base;   base += align16((size_t)V * 4);
    }
    float* enc_pers = (float*)base; base += align16((size_t)NPERS * D * 4);
    float* pnorms = (float*)base;   base += align16((size_t)NPERS * 4);
    float* st = (float*)base;

    // ---- cooperative mega-kernel path (r13) ----
    static int g_coop_grid = -2;
    if (g_coop_grid == -2) {
        g_coop_grid = -1;
        int dev = 0;
        if (hipGetDevice(&dev) == hipSuccess) {
            int coop = 0;
            hipDeviceGetAttribute(&coop, hipDeviceAttributeCooperativeLaunch, dev);
            hipDeviceProp_t prop;
            if (coop && hipGetDeviceProperties(&prop, dev) == hipSuccess) {
                int nbpcu = 0;
                if (hipOccupancyMaxActiveBlocksPerMultiprocessor(
                        &nbpcu, mega_kernel, 256, 0) == hipSuccess && nbpcu > 0) {
                    long g = (long)nbpcu * prop.multiProcessorCount;
                    if (g > 1024) g = 1024;       // r10: atomic-reducer cap
                    if (g >= 16) g_coop_grid = (int)g;
                }
            }
        }
    }
    if (stored && g_coop_grid > 0) {
        int Vv = V, NM = NMEM, NC = NCAND, NP = NPERS, LQv = LQ;
        const float* sembv = semb; const float* cembv = cemb;
        const int* xsv = xs; const int* cav = cands; const int* pev = pers;
        const int* kev = keys; const int* vav = values;
        const float* RWv = RW; const float* R2Wv = R2W;
        void* args[] = {(void*)&sembv, (void*)&cembv, (void*)&xsv, (void*)&cav,
                        (void*)&pev, (void*)&kev, (void*)&vav, (void*)&RWv,
                        (void*)&R2Wv, (void*)&tbl16s, (void*)&vb, (void*)&knp,
                        (void*)&sv, (void*)&enc_pers, (void*)&pnorms, (void*)&st,
                        (void*)&out, (void*)&Vv, (void*)&NM, (void*)&NC,
                        (void*)&NP, (void*)&LQv};
        if (hipLaunchCooperativeKernel(mega_kernel, dim3(g_coop_grid), dim3(256),
                                       args, 0, stream) == hipSuccess) {
            (void)n_in; (void)out_size; (void)ev;
            return;
        }
    }

    // ---- fallback: previous 15-kernel pipeline (known-good, 337us) ----
    if (stored) {
        {
            int n = V * 64;
            table_to_bf16_s<<<(n + THR - 1) / THR, THR, 0, stream>>>(semb, tbl16s, V);
        }
        {
            int ngroup = NMEM / 4;
            int blocks = (ngroup + 3) / 4;
            for (int s = 0; s < 4; ++s) {
                kv_slice_pass<20><<<blocks, THR, 0, stream>>>(
                    tbl16s + (size_t)s * V * 32, keys, values, NMEM,
                    vb + (size_t)s * NMEM * 32, knp, s);
            }
        }
        {
            int npairs = (NPERS + 2) / 2;
            int blocks = (npairs + 3) / 4;
            encode_small_p<<<blocks, THR, 0, stream>>>(semb, pers, NPERS, L, xs,
                                                       LQ, enc_pers, pnorms, st);
        }
        persona_hop<<<1, 128, 0, stream>>>(enc_pers, pnorms, RW, st, NPERS);
        a2_s<<<2048, THR, 0, stream>>>(tbl16s, st, sv, V);
        b2e<<<NMEM / THR, THR, 0, stream>>>(sv, keys, knp, st, ev, NMEM);
        cv_acc<<<1024, THR, 0, stream>>>(vb, ev, st, NMEM);
        mid_hop<<<1, 128, 0, stream>>>(RW, R2W, enc_pers, pnorms, st, NPERS);
        a2_s<<<2048, THR, 0, stream>>>(tbl16s, st, sv, V);
        b2e<<<NMEM / THR, THR, 0, stream>>>(sv, keys, knp, st, ev, NMEM);
        cv_acc<<<1024, THR, 0, stream>>>(vb, ev, st, NMEM);
        finish_hop<<<1, 128, 0, stream>>>(R2W, st);
        int nblk5 = (((NCAND + 1) / 2) + 3) / 4;
        k5_final<<<nblk5, THR, 0, stream>>>(cemb, cands, NCAND, st, out);
        (void)n_in; (void)out_size;
        return;
    }

    {
        int npairs = (NPERS + 2) / 2;
        int blocks = (npairs + 3) / 4;
        encode_small_p<<<blocks, THR, 0, stream>>>(semb, pers, NPERS, L, xs,
                                                   LQ, enc_pers, pnorms, st);
    }
    persona_hop<<<1, 128, 0, stream>>>(enc_pers, pnorms, RW, st, NPERS);
    big_att_rc<<<1024, THR, 0, stream>>>(semb, keys, values, st, NMEM);
    mid_hop<<<1, 128, 0, stream>>>(RW, R2W, enc_pers, pnorms, st, NPERS);
    big_att_rc<<<1024, THR, 0, stream>>>(semb, keys, values, st, NMEM);
    finish_hop<<<1, 128, 0, stream>>>(R2W, st);
    int nblk5 = (((NCAND + 1) / 2) + 3) / 4;
    k5_final<<<nblk5, THR, 0, stream>>>(cemb, cands, NCAND, st, out);

    (void)n_in; (void)out_size;
}

// Round 2
// 313.866 us; speedup vs baseline: 3.0993x; 3.0993x over previous
//
#include <hip/hip_runtime.h>
#include <math.h>
#include <stdint.h>

#define D 128
#define EPS 1e-6f
typedef unsigned short u16;

// ---------------------------------------------------------------------------
// state layout (floats), 16B-aligned base:
//   st[0..127]   : q
//   st[128..255] : q_plus
//   st[256..383] : hop accumulator (device atomicAdd targets)
//   st[384]      : ||q||   st[385] : ||q_plus||   st[386] : sum-of-exp
// Rules learned: no device fences after bulk writes (r6, ~100us); no global
// atomic scatters (r8, ~84ns/atomic); gather time ~= TCC bytes / 3.8 TB/s
// (r9, measured on 64B-scattered quarter-wave gathers); reducer grids <= 1024
// blocks (r10); single-block serial gathers are ~60us latency traps (r11);
// r14: cooperative grid.sync x11 on 1024 blocks = 972us total (vs 337us as
// separate launches) — grid.sync >> launch gap here; never serialize the
// whole pipeline behind cooperative sync. The old 337us was ~80% real work:
// dominant term = 672MB of KV gather traffic. This round: row-major table,
// half-wave-per-row CONTIGUOUS 256B gathers, single KV pass (ids read once,
// knorm one-pass), b2e+cv fused, finish_hop folded into k5.
// ---------------------------------------------------------------------------

__device__ __forceinline__ float wave_sum(float v) {
#pragma unroll
    for (int off = 32; off > 0; off >>= 1) v += __shfl_xor(v, off, 64);
    return v;
}
__device__ __forceinline__ float halfwave_sum(float v) {
#pragma unroll
    for (int off = 16; off > 0; off >>= 1) v += __shfl_xor(v, off, 32);
    return v;
}

__device__ __forceinline__ float bf2f(u16 h) {
    union { unsigned u; float f; } x;
    x.u = ((unsigned)h) << 16;
    return x.f;
}
__device__ __forceinline__ float bflo(unsigned u) { return bf2f((u16)(u & 0xffff)); }
__device__ __forceinline__ float bfhi(unsigned u) { return bf2f((u16)(u >> 16)); }
__device__ __forceinline__ u16 f2bf(float f) {  // round-to-nearest-even
    union { float f; unsigned u; } x;
    x.f = f;
    unsigned u = x.u;
    return (u16)((u + 0x7fff + ((u >> 16) & 1)) >> 16);
}
__device__ __forceinline__ unsigned pack2(float a, float b) {
    return (unsigned)f2bf(a) | ((unsigned)f2bf(b) << 16);
}

// ===========================================================================
// prep_k: blocks [0, nbK) convert fp32 table -> bf16 ROW-MAJOR (coalesced
// both sides); blocks [nbK, nbK+3) do the small encodes (persona rows + q).
// ===========================================================================
__global__ void prep_k(const float* __restrict__ semb, u16* __restrict__ tbl,
                       int V, const int* __restrict__ pers, int NP,
                       const int* __restrict__ xs, int LQ,
                       float* __restrict__ enc_pers, float* __restrict__ pnorms,
                       float* __restrict__ st, int nbK) {
    const int tid = threadIdx.x;
    const int bid = blockIdx.x;
    if (bid < nbK) {
        const int n = V * 64;  // channel-pairs
        const int stride = nbK * 256;
        for (int i = bid * 256 + tid; i < n; i += stride) {
            const int v = i >> 6;
            const int c2 = i & 63;
            const float2 ab = *(const float2*)(semb + (long)v * D + 2 * c2);
            *(unsigned*)(tbl + (long)v * D + 2 * c2) = pack2(ab.x, ab.y);
        }
    } else {
        const int lane = tid & 63;
        const int half = lane >> 5;
        const int hl = lane & 31;
        const int w0 = (bid - nbK) * 4 + (tid >> 6);
        const int npr = NP + 1;  // +1 virtual q row
        const int npairs = (npr + 1) >> 1;
        for (int w = w0; w < npairs; w += 12) {
            const int row = 2 * w + half;
            const bool valid = row < npr;
            const int rowc = valid ? row : NP;
            const bool isq = (rowc == NP);
            const int* ids = isq ? xs : (pers + (long)rowc * 20);
            const int L = isq ? LQ : 20;
            int myid = 0;
            if (hl < L) myid = ids[hl];
            float4 acc = {0.f, 0.f, 0.f, 0.f};
            for (int t = 0; t < L; ++t) {
                const int idx = __shfl(myid, (half << 5) + t, 64);
                const float4 e = *(const float4*)(semb + (long)idx * D + 4 * hl);
                acc.x += e.x; acc.y += e.y; acc.z += e.z; acc.w += e.w;
            }
            if (valid) {
                float* outp = isq ? st : (enc_pers + (long)rowc * D);
                *(float4*)(outp + 4 * hl) = acc;
                float sq = acc.x * acc.x + acc.y * acc.y + acc.z * acc.z + acc.w * acc.w;
                sq = halfwave_sum(sq);
                if (hl == 0) {
                    if (isq) st[384] = sqrtf(sq);
                    else pnorms[rowc] = sqrtf(sq);
                }
            }
        }
    }
}

// ===========================================================================
// persona hop as device fn (runs on block 0 of kvp_k, hidden under KV pass)
// ===========================================================================
__device__ void persona_dev(const float* __restrict__ pers_rows,
                            const float* __restrict__ pnorms,
                            const float* __restrict__ W, float* __restrict__ st,
                            int NP, float* smem, int tid) {
    float* qsh = smem;          // 128
    float* qh = smem + 128;     // 128
    float* att = smem + 256;    // 64
    float* red = smem + 320;    // 2
    if (tid < D) qsh[tid] = st[tid];
    __syncthreads();
    if (tid < NP) {
        float dot = 0.f;
        const float* pr = pers_rows + (long)tid * D;
        for (int d2 = 0; d2 < D; ++d2) dot += pr[d2] * qsh[d2];
        att[tid] = dot / fmaxf(pnorms[tid] * st[384], EPS);
    }
    __syncthreads();
    if (tid == 0) {
        float m = -1e30f;
        for (int p = 0; p < NP; ++p) m = fmaxf(m, att[p]);
        float s = 0.f;
        for (int p = 0; p < NP; ++p) { att[p] = __expf(att[p] - m); s += att[p]; }
        float inv = 1.f / s;
        for (int p = 0; p < NP; ++p) att[p] *= inv;
    }
    __syncthreads();
    if (tid < D) {
        float h = 0.f;
        for (int p = 0; p < NP; ++p) h += att[p] * pers_rows[(long)p * D + tid];
        qh[tid] = qsh[tid] + h;
    }
    __syncthreads();
    float qp = 0.f;
    if (tid < D) {
        for (int d2 = 0; d2 < D; ++d2) qp += W[(long)tid * D + d2] * qh[d2];
        st[128 + tid] = qp;
    }
    float sq = wave_sum(qp * qp);
    if ((tid & 63) == 0 && tid < 128) red[tid >> 6] = sq;
    __syncthreads();
    if (tid == 0) st[385] = sqrtf(red[0] + red[1]);
    if (tid < D) st[256 + tid] = 0.f;
    if (tid == 0) st[386] = 0.f;
}

// ===========================================================================
// kvp_k: single-pass KV encode. Half-wave (32 lanes) owns one memory row;
// lane hl covers channels 4hl..4hl+3 (ushort4 = contiguous 256B per row per
// load — vs the old 4x slice passes with 4 scattered 64B segments/instr).
// Produces vb (row-major bf16) and knorms (full norm, one pass).
// Block 0 runs persona_hop instead (depends only on prep_k, like KV).
// ===========================================================================
__global__ void kvp_k(const u16* __restrict__ tbl, const int* __restrict__ kids,
                      const int* __restrict__ vids, int N,
                      u16* __restrict__ vb, float* __restrict__ knorms,
                      const float* __restrict__ enc_pers,
                      const float* __restrict__ pnorms,
                      const float* __restrict__ RW, float* __restrict__ st,
                      int NP) {
    __shared__ float smem[336];
    const int tid = threadIdx.x;
    const int bid = blockIdx.x;
    if (bid == 0) {
        persona_dev(enc_pers, pnorms, RW, st, NP, smem, tid);
        return;
    }
    const int lane = tid & 63;
    const int half = lane >> 5;
    const int hl = lane & 31;
    const int ghw = ((bid - 1) * 256 + tid) >> 5;   // global half-wave
    const int nhw = ((gridDim.x - 1) * 256) >> 5;
    for (int i = ghw; i < N; i += nhw) {
        int kid = 0, vid = 0;
        if (hl < 20) {
            kid = kids[(long)i * 20 + hl];
            vid = vids[(long)i * 20 + hl];
        }
        float k0 = 0.f, k1 = 0.f, k2 = 0.f, k3 = 0.f;
        float v0 = 0.f, v1 = 0.f, v2 = 0.f, v3 = 0.f;
#pragma unroll
        for (int t = 0; t < 20; ++t) {
            const int kj = __shfl(kid, (half << 5) + t, 64);
            const int vj = __shfl(vid, (half << 5) + t, 64);
            const ushort4 ke = *(const ushort4*)(tbl + (long)kj * D + 4 * hl);
            const ushort4 ve = *(const ushort4*)(tbl + (long)vj * D + 4 * hl);
            k0 += bf2f(ke.x); k1 += bf2f(ke.y); k2 += bf2f(ke.z); k3 += bf2f(ke.w);
            v0 += bf2f(ve.x); v1 += bf2f(ve.y); v2 += bf2f(ve.z); v3 += bf2f(ve.w);
        }
        uint2 pv;
        pv.x = pack2(v0, v1);
        pv.y = pack2(v2, v3);
        *(uint2*)(vb + (long)i * D + 4 * hl) = pv;
        float sq = halfwave_sum(k0 * k0 + k1 * k1 + k2 * k2 + k3 * k3);
        if (hl == 0) knorms[i] = sqrtf(sq);
    }
}

// ===========================================================================
// a2_k: s[v] = T16[v] . q_plus. Row-major: 64 lanes x uint = 256B contiguous.
// ===========================================================================
__global__ void a2_k(const u16* __restrict__ tbl, const float* __restrict__ st,
                     float* __restrict__ s, int V) {
    const int lane = threadIdx.x & 63;
    const float2 qp2 = *(const float2*)(st + 128 + 2 * lane);
    const int gw = (int)((blockIdx.x * blockDim.x + threadIdx.x) >> 6);
    const int nw = (int)((gridDim.x * blockDim.x) >> 6);
    for (int v = gw; v < V; v += nw) {
        const unsigned u = *(const unsigned*)(tbl + (long)v * D + 2 * lane);
        float d = bflo(u) * qp2.x + bfhi(u) * qp2.y;
        d = wave_sum(d);
        if (lane == 0) s[v] = d;
    }
}

// ===========================================================================
// attcv_k: fused b2e + cv. Half-wave per row: 20-lane sv gather -> dot ->
// e = exp(cos) in-register -> accumulate e * vb_row (row-major uint2 loads).
// GRID <= 1024 BLOCKS (r10: ends in st atomics).
// ===========================================================================
__global__ void attcv_k(const float* __restrict__ sv, const int* __restrict__ kids,
                        const float* __restrict__ knorms, const u16* __restrict__ vb,
                        float* __restrict__ st, int N) {
    __shared__ float smem[129];
    const int tid = threadIdx.x;
    const int lane = tid & 63;
    const int half = lane >> 5;
    const int hl = lane & 31;
    const float qpn = st[385];
    const int ghw = (int)((blockIdx.x * blockDim.x + tid) >> 5);
    const int nhw = (int)((gridDim.x * blockDim.x) >> 5);
    float a0 = 0.f, a1 = 0.f, a2 = 0.f, a3 = 0.f;
    float esum = 0.f;
    for (int i = ghw; i < N; i += nhw) {
        float partial = 0.f;
        if (hl < 20) partial = sv[kids[(long)i * 20 + hl]];
        const float dot = halfwave_sum(partial);
        const float c = dot / fmaxf(knorms[i] * qpn, EPS);
        const float e = __expf(c);
        const uint2 vh = *(const uint2*)(vb + (long)i * D + 4 * hl);
        a0 += e * bflo(vh.x);
        a1 += e * bfhi(vh.x);
        a2 += e * bflo(vh.y);
        a3 += e * bfhi(vh.y);
        if (hl == 0) esum += e;
    }
    a0 += __shfl_xor(a0, 32, 64);
    a1 += __shfl_xor(a1, 32, 64);
    a2 += __shfl_xor(a2, 32, 64);
    a3 += __shfl_xor(a3, 32, 64);
    esum += __shfl_xor(esum, 32, 64);
    if (tid < 129) smem[tid] = 0.f;
    __syncthreads();
    if (half == 0) {
        atomicAdd(&smem[4 * hl + 0], a0);
        atomicAdd(&smem[4 * hl + 1], a1);
        atomicAdd(&smem[4 * hl + 2], a2);
        atomicAdd(&smem[4 * hl + 3], a3);
        if (hl == 0) atomicAdd(&smem[128], esum);
    }
    __syncthreads();
    if (tid < 128) atomicAdd(&st[256 + tid], smem[tid]);
    if (tid == 128) atomicAdd(&st[386], smem[128]);
}

// ===========================================================================
// mid_hop (1 block, 128 threads) — known-good.
// ===========================================================================
__global__ void mid_hop(const float* __restrict__ W1, const float* __restrict__ W2,
                        const float* __restrict__ pers_rows,
                        const float* __restrict__ pnorms,
                        float* __restrict__ st, int NP) {
    __shared__ float qh[D];
    __shared__ float qsh[D];
    __shared__ float att[64];
    __shared__ float red[2];
    int tid = threadIdx.x;
    float inv = 1.f / st[386];
    qh[tid] = st[128 + tid] + st[256 + tid] * inv;
    __syncthreads();
    float qn = 0.f;
    for (int d2 = 0; d2 < D; ++d2) qn += W1[tid * D + d2] * qh[d2];
    qsh[tid] = qn;
    st[tid] = qn;
    float sq = wave_sum(qn * qn);
    if ((tid & 63) == 0) red[tid >> 6] = sq;
    __syncthreads();
    float qnorm = sqrtf(red[0] + red[1]);
    if (tid == 0) st[384] = qnorm;
    if (tid < NP) {
        float dot = 0.f;
        for (int d2 = 0; d2 < D; ++d2) dot += pers_rows[tid * D + d2] * qsh[d2];
        att[tid] = dot / fmaxf(pnorms[tid] * qnorm, EPS);
    }
    __syncthreads();
    if (tid == 0) {
        float m = -1e30f;
        for (int p = 0; p < NP; ++p) m = fmaxf(m, att[p]);
        float s = 0.f;
        for (int p = 0; p < NP; ++p) { att[p] = __expf(att[p] - m); s += att[p]; }
        float is = 1.f / s;
        for (int p = 0; p < NP; ++p) att[p] *= is;
    }
    __syncthreads();
    float h = 0.f;
    for (int p = 0; p < NP; ++p) h += att[p] * pers_rows[p * D + tid];
    qh[tid] = qsh[tid] + h;
    __syncthreads();
    float qp = 0.f;
    for (int d2 = 0; d2 < D; ++d2) qp += W2[tid * D + d2] * qh[d2];
    st[128 + tid] = qp;
    float sq2 = wave_sum(qp * qp);
    if ((tid & 63) == 0) red[tid >> 6] = sq2;
    __syncthreads();
    if (tid == 0) st[385] = sqrtf(red[0] + red[1]);
    st[256 + tid] = 0.f;
    if (tid == 0) st[386] = 0.f;
}

// ===========================================================================
// k5f: finish_hop computed redundantly per-block in smem (removes a launch;
// W2 is L2-broadcast), then fused candidate gather + cosine.
// ===========================================================================
__global__ void k5f(const float* __restrict__ W2, const float* __restrict__ cemb,
                    const int* __restrict__ cands, int NC,
                    const float* __restrict__ st, float* __restrict__ out) {
    __shared__ float qv[D];
    __shared__ float qhsh[D];
    __shared__ float red[2];
    __shared__ float qns;
    const int tid = threadIdx.x;
    // ---- finish-hop prologue (every block; deterministic identical result)
    const float inv = 1.f / st[386];
    if (tid < D) qhsh[tid] = st[128 + tid] + st[256 + tid] * inv;
    __syncthreads();
    float qn = 0.f;
    if (tid < D) {
        for (int d2 = 0; d2 < D; ++d2) qn += W2[(long)tid * D + d2] * qhsh[d2];
        qv[tid] = qn;
    }
    float sq = wave_sum(qn * qn);
    if ((tid & 63) == 0 && tid < 128) red[tid >> 6] = sq;
    __syncthreads();
    if (tid == 0) qns = sqrtf(red[0] + red[1]);
    __syncthreads();
    // ---- candidate gather + cosine
    const int lane = tid & 63;
    const int half = lane >> 5;
    const int hl = lane & 31;
    const int gw = (int)((blockIdx.x * blockDim.x + tid) >> 6);
    const int nw = (int)((gridDim.x * blockDim.x) >> 6);
    const float4 q4 = *(const float4*)(qv + 4 * hl);
    const float qnf = qns;
    const int npair = (NC + 1) >> 1;
    for (int p = gw; p < npair; p += nw) {
        const int row = 2 * p + half;
        const bool valid = row < NC;
        const int rowc = valid ? row : (NC - 1);
        int myid = 0;
        if (hl < 20) myid = cands[(long)rowc * 20 + hl];
        float4 acc = {0.f, 0.f, 0.f, 0.f};
#pragma unroll
        for (int t = 0; t < 20; ++t) {
            const int idx = __shfl(myid, (half << 5) + t, 64);
            const float4 e = *(const float4*)(cemb + (long)idx * D + 4 * hl);
            acc.x += e.x; acc.y += e.y; acc.z += e.z; acc.w += e.w;
        }
        float dot = halfwave_sum(acc.x * q4.x + acc.y * q4.y +
                                 acc.z * q4.z + acc.w * q4.w);
        float nsq = halfwave_sum(acc.x * acc.x + acc.y * acc.y +
                                 acc.z * acc.z + acc.w * acc.w);
        if (valid && hl == 0) out[row] = dot / fmaxf(sqrtf(nsq) * qnf, EPS);
    }
}

// ===========================================================================
// Fallback path kernels (no/undersized workspace): fp32 on-the-fly.
// ===========================================================================
__global__ void encode_small_p(const float* __restrict__ emb,
                               const int* __restrict__ pers, int NP, int LP,
                               const int* __restrict__ xs, int LQ,
                               float* __restrict__ pers_rows,
                               float* __restrict__ pnorms,
                               float* __restrict__ st) {
    const int lane = threadIdx.x & 63;
    const int half = lane >> 5;
    const int hl = lane & 31;
    int gw = (int)((blockIdx.x * blockDim.x + threadIdx.x) >> 6);
    int nw = (int)((gridDim.x * blockDim.x) >> 6);
    const int npr = NP + 1;
    const int npairs = (npr + 1) >> 1;
    for (int p = gw; p < npairs; p += nw) {
        const int row = 2 * p + half;
        const bool valid = row < npr;
        const int rowc = valid ? row : NP;
        const bool isq = (rowc == NP);
        const int* ids = isq ? xs : (pers + (long)rowc * LP);
        const int L = isq ? LQ : LP;
        int myid = 0;
        if (hl < L) myid = ids[hl];
        float4 acc = {0.f, 0.f, 0.f, 0.f};
        for (int t = 0; t < L; ++t) {
            const int idx = __shfl(myid, (half << 5) + t, 64);
            const float4 e = *(const float4*)(emb + (long)idx * D + 4 * hl);
            acc.x += e.x; acc.y += e.y; acc.z += e.z; acc.w += e.w;
        }
        if (valid) {
            float* outp = isq ? st : (pers_rows + (long)rowc * D);
            *(float4*)(outp + 4 * hl) = acc;
            float sq = acc.x * acc.x + acc.y * acc.y + acc.z * acc.z + acc.w * acc.w;
            sq = halfwave_sum(sq);
            if (hl == 0) {
                if (isq) st[384] = sqrtf(sq);
                else pnorms[rowc] = sqrtf(sq);
            }
        }
    }
}

__global__ void persona_hop(const float* __restrict__ pers_rows,
                            const float* __restrict__ pnorms,
                            const float* __restrict__ W,
                            float* __restrict__ st, int NP) {
    __shared__ float smem[336];
    persona_dev(pers_rows, pnorms, W, st, NP, smem, (int)threadIdx.x);
}

__global__ void finish_hop(const float* __restrict__ W, float* __restrict__ st) {
    __shared__ float qh[D];
    __shared__ float red[2];
    int tid = threadIdx.x;
    float inv = 1.f / st[386];
    qh[tid] = st[128 + tid] + st[256 + tid] * inv;
    __syncthreads();
    float qn = 0.f;
    for (int d2 = 0; d2 < D; ++d2) qn += W[tid * D + d2] * qh[d2];
    st[tid] = qn;
    float sq = wave_sum(qn * qn);
    if ((tid & 63) == 0) red[tid >> 6] = sq;
    __syncthreads();
    if (tid == 0) st[384] = sqrtf(red[0] + red[1]);
}

__global__ void k5_final(const float* __restrict__ cemb,
                         const int* __restrict__ cands, int NC,
                         const float* __restrict__ st, float* __restrict__ out) {
    const int lane = threadIdx.x & 63;
    const int half = lane >> 5;
    const int hl = lane & 31;
    const int gw = (int)((blockIdx.x * blockDim.x + threadIdx.x) >> 6);
    const int nw = (int)((gridDim.x * blockDim.x) >> 6);
    const float4 q4 = *(const float4*)(st + 4 * hl);
    const float qn = st[384];
    const int npair = (NC + 1) >> 1;
    for (int p = gw; p < npair; p += nw) {
        const int row = 2 * p + half;
        const bool valid = row < NC;
        const int rowc = valid ? row : (NC - 1);
        int myid = 0;
        if (hl < 20) myid = cands[(long)rowc * 20 + hl];
        float4 acc = {0.f, 0.f, 0.f, 0.f};
#pragma unroll
        for (int t = 0; t < 20; ++t) {
            const int idx = __shfl(myid, (half << 5) + t, 64);
            const float4 e = *(const float4*)(cemb + (long)idx * D + 4 * hl);
            acc.x += e.x; acc.y += e.y; acc.z += e.z; acc.w += e.w;
        }
        float dot = halfwave_sum(acc.x * q4.x + acc.y * q4.y +
                                 acc.z * q4.z + acc.w * q4.w);
        float nsq = halfwave_sum(acc.x * acc.x + acc.y * acc.y +
                                 acc.z * acc.z + acc.w * acc.w);
        if (valid && hl == 0) out[row] = dot / fmaxf(sqrtf(nsq) * qn, EPS);
    }
}

__global__ void big_att_rc(const float* __restrict__ emb,
                           const int* __restrict__ kids,
                           const int* __restrict__ vids,
                           float* __restrict__ st, int N) {
    __shared__ float s[129];
    const int tid = threadIdx.x;
    const int lane = tid & 63;
    const int half = lane >> 5;
    const int hl = lane & 31;
    const int gw = (int)((blockIdx.x * blockDim.x + tid) >> 6);
    const int nw = (int)((gridDim.x * blockDim.x) >> 6);
    const float4 qp = *(const float4*)(st + 128 + 4 * hl);
    const float qpn = st[385];
    float4 hacc = {0.f, 0.f, 0.f, 0.f};
    float esum = 0.f;
    const int npair = (N + 1) >> 1;
    for (int p = gw; p < npair; p += nw) {
        const int row = 2 * p + half;
        const bool valid = row < N;
        const int rowc = valid ? row : (N - 1);
        int kid = 0, vid = 0;
        if (hl < 20) {
            kid = kids[(long)rowc * 20 + hl];
            vid = vids[(long)rowc * 20 + hl];
        }
        float4 ka = {0.f, 0.f, 0.f, 0.f}, va = {0.f, 0.f, 0.f, 0.f};
#pragma unroll
        for (int t = 0; t < 20; ++t) {
            const int ki = __shfl(kid, (half << 5) + t, 64);
            const int vi = __shfl(vid, (half << 5) + t, 64);
            const float4 ke = *(const float4*)(emb + (long)ki * D + 4 * hl);
            const float4 ve = *(const float4*)(emb + (long)vi * D + 4 * hl);
            ka.x += ke.x; ka.y += ke.y; ka.z += ke.z; ka.w += ke.w;
            va.x += ve.x; va.y += ve.y; va.z += ve.z; va.w += ve.w;
        }
        float nsq = halfwave_sum(ka.x * ka.x + ka.y * ka.y + ka.z * ka.z + ka.w * ka.w);
        float dot = halfwave_sum(ka.x * qp.x + ka.y * qp.y + ka.z * qp.z + ka.w * qp.w);
        const float c = dot / fmaxf(sqrtf(nsq) * qpn, EPS);
        float e = __expf(c);
        if (!valid) e = 0.f;
        hacc.x += e * va.x; hacc.y += e * va.y;
        hacc.z += e * va.z; hacc.w += e * va.w;
        if (hl == 0) esum += e;
    }
    hacc.x += __shfl_xor(hacc.x, 32, 64);
    hacc.y += __shfl_xor(hacc.y, 32, 64);
    hacc.z += __shfl_xor(hacc.z, 32, 64);
    hacc.w += __shfl_xor(hacc.w, 32, 64);
    esum += __shfl_xor(esum, 32, 64);
    if (tid < 129) s[tid] = 0.f;
    __syncthreads();
    if (half == 0) {
        atomicAdd(&s[4 * hl + 0], hacc.x);
        atomicAdd(&s[4 * hl + 1], hacc.y);
        atomicAdd(&s[4 * hl + 2], hacc.z);
        atomicAdd(&s[4 * hl + 3], hacc.w);
        if (hl == 0) atomicAdd(&s[128], esum);
    }
    __syncthreads();
    if (tid < 128) atomicAdd(&st[256 + tid], s[tid]);
    if (tid == 128) atomicAdd(&st[386], s[128]);
}

static inline size_t align16(size_t b) { return (b + 15) & ~(size_t)15; }

extern "C" void kernel_launch(void* const* d_in, const int* in_sizes, int n_in,
                              void* d_out, int out_size, void* d_ws, size_t ws_size,
                              hipStream_t stream) {
    const int* xs = (const int*)d_in[0];
    const int* cands = (const int*)d_in[1];
    const int* pers = (const int*)d_in[2];
    const int* keys = (const int*)d_in[3];
    const int* values = (const int*)d_in[4];
    const float* semb = (const float*)d_in[6];
    const float* cemb = (const float*)d_in[7];
    const float* RW = (const float*)d_in[8];
    const float* R2W = (const float*)d_in[9];
    float* out = (float*)d_out;

    const int L = 20;
    const int LQ = in_sizes[0];
    const int VD = in_sizes[6];         // V*D
    const int V = VD / D;               // 50000
    const int NMEM = in_sizes[3] / L;   // 65536
    const int NCAND = in_sizes[1] / L;  // 10000
    const int NPERS = in_sizes[2] / L;  // 20

    size_t need = align16((size_t)VD * 2) + align16((size_t)NMEM * D * 2) +
                  align16((size_t)NMEM * 4) * 2 + align16((size_t)V * 4) +
                  align16((size_t)NPERS * D * 4) + align16((size_t)NPERS * 4) +
                  512 * 4;
    bool stored = (d_ws != nullptr) && (ws_size >= need) && (NMEM % 4 == 0) &&
                  ((VD & 3) == 0) && (LQ <= 32);

    const int THR = 256;
    char* base = (char*)d_ws;
    u16 *tbl16 = nullptr, *vb = nullptr;
    float *knorms = nullptr, *sv = nullptr;
    if (stored) {
        tbl16 = (u16*)base;  base += align16((size_t)VD * 2);        // row-major
        vb = (u16*)base;     base += align16((size_t)NMEM * D * 2);  // row-major
        knorms = (float*)base; base += align16((size_t)NMEM * 4);
        base += align16((size_t)NMEM * 4);                           // (spare)
        sv = (float*)base;   base += align16((size_t)V * 4);
    }
    float* enc_pers = (float*)base; base += align16((size_t)NPERS * D * 4);
    float* pnorms = (float*)base;   base += align16((size_t)NPERS * 4);
    float* st = (float*)base;

    if (stored) {
        const int nbK = 2048;
        // 1. prep: bf16 row-major convert || small encodes
        prep_k<<<nbK + 3, THR, 0, stream>>>(semb, tbl16, V, pers, NPERS, xs, LQ,
                                            enc_pers, pnorms, st, nbK);
        // 2. single-pass KV encode (contiguous 256B gathers) || persona_hop
        kvp_k<<<2048, THR, 0, stream>>>(tbl16, keys, values, NMEM, vb, knorms,
                                        enc_pers, pnorms, RW, st, NPERS);
        // 3-4. hop 1
        a2_k<<<2048, THR, 0, stream>>>(tbl16, st, sv, V);
        attcv_k<<<1024, THR, 0, stream>>>(sv, keys, knorms, vb, st, NMEM);  // r10
        // 5. mid hop
        mid_hop<<<1, 128, 0, stream>>>(RW, R2W, enc_pers, pnorms, st, NPERS);
        // 6-7. hop 2
        a2_k<<<2048, THR, 0, stream>>>(tbl16, st, sv, V);
        attcv_k<<<1024, THR, 0, stream>>>(sv, keys, knorms, vb, st, NMEM);  // r10
        // 8. finish-hop (per-block) + candidates
        int nblk5 = (((NCAND + 1) / 2) + 3) / 4;
        k5f<<<nblk5, THR, 0, stream>>>(R2W, cemb, cands, NCAND, st, out);
        (void)n_in; (void)out_size;
        return;
    }

    // -------- fallback: fp32 on-the-fly gather --------
    {
        int npairs = (NPERS + 2) / 2;
        int blocks = (npairs + 3) / 4;
        encode_small_p<<<blocks, THR, 0, stream>>>(semb, pers, NPERS, L, xs,
                                                   LQ, enc_pers, pnorms, st);
    }
    persona_hop<<<1, 128, 0, stream>>>(enc_pers, pnorms, RW, st, NPERS);
    big_att_rc<<<1024, THR, 0, stream>>>(semb, keys, values, st, NMEM);
    mid_hop<<<1, 128, 0, stream>>>(RW, R2W, enc_pers, pnorms, st, NPERS);
    big_att_rc<<<1024, THR, 0, stream>>>(semb, keys, values, st, NMEM);
    finish_hop<<<1, 128, 0, stream>>>(R2W, st);
    int nblk5 = (((NCAND + 1) / 2) + 3) / 4;
    k5_final<<<nblk5, THR, 0, stream>>>(cemb, cands, NCAND, st, out);

    (void)n_in; (void)out_size;
}